// Round 5
// baseline (78.711 us; speedup 1.0000x reference)
//
#include <hip/hip_runtime.h>
#include <math.h>

#define NF 8
#define HID 128
#define PPW 32     // points per wave per iteration (two 16-pt MFMA column groups)
#define TILE 1024  // points per k_main block: 4 waves x 32 pts x 8 iters
#define NIT 8

typedef _Float16 f16;
typedef _Float16 h2 __attribute__((ext_vector_type(2)));
typedef _Float16 f16x8 __attribute__((ext_vector_type(8)));
typedef float f32x4 __attribute__((ext_vector_type(4)));
typedef unsigned int u32;
typedef u32 u32x2 __attribute__((ext_vector_type(2)));
typedef u32 u32x4 __attribute__((ext_vector_type(4)));

__device__ __forceinline__ u32 pk(float a, float b) {
    return __builtin_bit_cast(u32, __builtin_amdgcn_cvt_pkrtz(a, b));
}
__device__ __forceinline__ float dot2a(u32 a, u32 b, float c) {
    return __builtin_amdgcn_fdot2(__builtin_bit_cast(h2, a),
                                  __builtin_bit_cast(h2, b), c, false);
}
__device__ __forceinline__ void lfence() {
    asm volatile("s_waitcnt lgkmcnt(0)" ::: "memory");
}

// ws int layout:
//   [0..7] counts, [8..15] starts, [16..23] tile-prefix, [24] total tiles
//   [32 .. 32+NB*8) per-block counts;  [32+NB*8 ..) perm

__device__ __forceinline__ int assign_field(float px, float py, float pz,
                                            const float* __restrict__ cen) {
    int best = 0;
    float bd = 3.4e38f;
#pragma unroll
    for (int k = 0; k < NF; ++k) {
        float dx = px - cen[k * 3 + 0];
        float dy = py - cen[k * 3 + 1];
        float dz = pz - cen[k * 3 + 2];
        float d = fmaf(dx, dx, fmaf(dy, dy, dz * dz));
        if (d < bd) { bd = d; best = k; }
    }
    return best;
}

// 512 threads, 4 points per thread; per-block counts only (no global atomics).
__global__ void k_count(const float* __restrict__ pos, const float* __restrict__ cen,
                        int n, int* __restrict__ blockcnt) {
    __shared__ int lc[NF];
    int tid = threadIdx.x;
    if (tid < NF) lc[tid] = 0;
    __syncthreads();
    int i4 = blockIdx.x * blockDim.x + tid;
    int base = i4 * 4;
    if (base + 3 < n) {
        const float4* p4 = (const float4*)pos;
        float4 a = p4[i4 * 3 + 0];
        float4 b = p4[i4 * 3 + 1];
        float4 c = p4[i4 * 3 + 2];
        atomicAdd(&lc[assign_field(a.x, a.y, a.z, cen)], 1);
        atomicAdd(&lc[assign_field(a.w, b.x, b.y, cen)], 1);
        atomicAdd(&lc[assign_field(b.z, b.w, c.x, cen)], 1);
        atomicAdd(&lc[assign_field(c.y, c.z, c.w, cen)], 1);
    } else {
        for (int i = base; i < n; ++i)
            atomicAdd(&lc[assign_field(pos[3 * i], pos[3 * i + 1], pos[3 * i + 2], cen)], 1);
    }
    __syncthreads();
    if (tid < NF) blockcnt[blockIdx.x * NF + tid] = lc[tid];
}

// Fused scan+scatter: every block redundantly scans the (nb x 8) count table
// (2 KB from L2), derives its own write offsets, then scatters its 4-pt chunk.
// Block 0 also writes the ws header. 512 threads; wave f owns field f in scan.
__global__ void k_scatscan(const float* __restrict__ pos, const float* __restrict__ cen,
                           int n, int nb, int* __restrict__ ws) {
    const int tid = threadIdx.x;
    const int f = tid >> 6, lane = tid & 63;
    const int* c = ws + 32;
    int* perm = ws + 32 + nb * NF;
    __shared__ int totals[NF], pres[NF], starts[NF], cur[NF];

    int tot = 0, pre = 0;
    for (int b = lane; b < nb; b += 64) {
        int v = c[b * NF + f];
        tot += v;
        if (b < (int)blockIdx.x) pre += v;
    }
#pragma unroll
    for (int d = 1; d < 64; d <<= 1) {
        tot += __shfl_xor(tot, d, 64);
        pre += __shfl_xor(pre, d, 64);
    }
    if (lane == 0) { totals[f] = tot; pres[f] = pre; }
    __syncthreads();
    if (tid == 0) {
        int s = 0, tp = 0;
        for (int k = 0; k < NF; ++k) {
            starts[k] = s;
            if (blockIdx.x == 0) {
                ws[k] = totals[k];
                ws[8 + k] = s;
                ws[16 + k] = tp;
            }
            s += totals[k];
            tp += (totals[k] + TILE - 1) / TILE;
        }
        if (blockIdx.x == 0) ws[24] = tp;
    }
    __syncthreads();
    if (tid < NF) cur[tid] = starts[tid] + pres[tid];
    __syncthreads();

    int i4 = blockIdx.x * blockDim.x + tid;
    int base = i4 * 4;
    if (base + 3 < n) {
        const float4* p4 = (const float4*)pos;
        float4 a = p4[i4 * 3 + 0];
        float4 b = p4[i4 * 3 + 1];
        float4 cc = p4[i4 * 3 + 2];
        int f0 = assign_field(a.x, a.y, a.z, cen);
        int f1 = assign_field(a.w, b.x, b.y, cen);
        int f2 = assign_field(b.z, b.w, cc.x, cen);
        int f3 = assign_field(cc.y, cc.z, cc.w, cen);
        perm[atomicAdd(&cur[f0], 1)] = base;
        perm[atomicAdd(&cur[f1], 1)] = base + 1;
        perm[atomicAdd(&cur[f2], 1)] = base + 2;
        perm[atomicAdd(&cur[f3], 1)] = base + 3;
    } else {
        for (int i = base; i < n; ++i) {
            int ff = assign_field(pos[3 * i], pos[3 * i + 1], pos[3 * i + 2], cen);
            perm[atomicAdd(&cur[ff], 1)] = i;
        }
    }
}

// MFMA k_main, 32 points/wave/iter (two 16-col MFMA groups per fence-chain).
// Per-iter fence count unchanged vs R0 (4) -> per-point chain overhead halved
// (R4 showed the serial fence chain dominates; resident waves pinned ~8/CU).
// LDS 72.5 KB -> 2 blocks/CU -> 2 waves/SIMD -> 256-VGPR budget: no clamp,
// no spill (launch_bounds(256,2)).
// Gather: lane l owns point p32=l&31; lanes<32 also load pos, lanes>=32 dir;
// app half hf=l>>5 (16 floats) per lane.
// cin layout per point (72 halves): [0..2]=dir, [3]=1, [4..7]=0, [8..39]=app,
// [40..54]=geo, [55..63]=0 (only k=0..63 consumed). Wc1^T staged to match.
__global__ __launch_bounds__(256, 2) void k_main(
    const float* __restrict__ positions, const float* __restrict__ directions,
    const float* __restrict__ app,
    const float* __restrict__ Wd1, const float* __restrict__ bd1,
    const float* __restrict__ Wd2, const float* __restrict__ bd2,
    const float* __restrict__ Wc1, const float* __restrict__ bc1,
    const float* __restrict__ Wc2, const float* __restrict__ bc2,
    const int* __restrict__ ws, int nb, float* __restrict__ out) {
    const int b = blockIdx.x;
    if (b >= ws[24]) return;
    int f = 0;
#pragma unroll
    for (int k = 1; k < NF; ++k) if (b >= ws[16 + k]) f = k;
    const int tile = b - ws[16 + f];
    const int cnt = ws[f];
    const int start = ws[8 + f];
    const int* perm = ws + 32 + nb * NF;
    const int tid = threadIdx.x;
    const int w = tid >> 6, lane = tid & 63;
    const int pt = lane & 15, quad = lane >> 4;
    const int p32 = lane & 31;   // this lane's point slot (0..31)
    const int hf = lane >> 5;    // app half (0 or 1)

    __shared__ __align__(16) f16 sWc1t[HID * 72];    // [h][72] permuted   18 KB
    __shared__ __align__(16) u32 sWc2p[64 * 4];      // [hp][ch] pairs      1 KB
    __shared__ __align__(16) int sIdx[4][32];        //                   0.5 KB
    __shared__ __align__(16) u32 sPos[4][32][2];     // pk'd pos            1 KB
    __shared__ __align__(16) f16 sCin[4][32 * 72];   // per-wave           18 KB
    __shared__ __align__(16) f16 sH[4][32 * 136];    // per-wave           34 KB

    // ---- stage Wc1^T (permuted, f16) and Wc2 pairs ----
    if (tid < HID) {
        int h = tid;
        f16* row = &sWc1t[h * 72];
        const float* Wf = Wc1 + f * 50 * HID;
        row[0] = (f16)Wf[0 * HID + h];
        row[1] = (f16)Wf[1 * HID + h];
        row[2] = (f16)Wf[2 * HID + h];
        row[3] = (f16)bc1[f * HID + h];
        row[4] = 0; row[5] = 0; row[6] = 0; row[7] = 0;
        for (int a = 0; a < 32; ++a) row[8 + a] = (f16)Wf[(18 + a) * HID + h];
        for (int g = 0; g < 15; ++g) row[40 + g] = (f16)Wf[(3 + g) * HID + h];
        for (int z = 55; z < 72; ++z) row[z] = 0;
    }
    if (tid < 64) {
        int hp = tid;
        const float* W2 = Wc2 + f * HID * 3;
        sWc2p[hp * 4 + 0] = pk(W2[(2 * hp) * 3 + 0], W2[(2 * hp + 1) * 3 + 0]);
        sWc2p[hp * 4 + 1] = pk(W2[(2 * hp) * 3 + 1], W2[(2 * hp + 1) * 3 + 1]);
        sWc2p[hp * 4 + 2] = pk(W2[(2 * hp) * 3 + 2], W2[(2 * hp + 1) * 3 + 2]);
        sWc2p[hp * 4 + 3] = 0;
    }
    if (lane < 32) {  // zero cin pad zones, rows 0..31 (per-wave region)
        f16* row = &sCin[w][p32 * 72];
        u32x2 z2; z2.x = 0; z2.y = 0;
        *(u32x2*)&row[4] = z2;
        row[55] = 0;
        u32x4 z4; z4.x = 0; z4.y = 0; z4.z = 0; z4.w = 0;
        *(u32x4*)&row[56] = z4;
    }

    // ---- resident fragments (from global) ----
    u32 wd1a0[8], wd1a1[8];
    if (quad == 0) {
        const float* W1 = Wd1 + f * 3 * HID;
        const float* B1 = bd1 + f * HID;
#pragma unroll
        for (int mt = 0; mt < 8; ++mt) {
            int m = 16 * mt + pt;
            wd1a0[mt] = pk(W1[m], W1[HID + m]);
            wd1a1[mt] = pk(W1[2 * HID + m], B1[m]);
        }
    } else {
#pragma unroll
        for (int mt = 0; mt < 8; ++mt) { wd1a0[mt] = 0; wd1a1[mt] = 0; }
    }
    f16x8 wd2b[4];
    {
        const float* W2d = Wd2 + f * HID * 16;
#pragma unroll
        for (int s = 0; s < 4; ++s) {
            u32x4 v;
#pragma unroll
            for (int jp = 0; jp < 4; ++jp) {
                int k = quad * 8 + 32 * s + 2 * jp;
                v[jp] = pk(W2d[k * 16 + pt], W2d[(k + 1) * 16 + pt]);
            }
            wd2b[s] = __builtin_bit_cast(f16x8, v);
        }
    }
    const float bd2v = bd2[f * 16 + pt];
    const float c20 = bc2[f * 3 + 0], c21 = bc2[f * 3 + 1], c22 = bc2[f * 3 + 2];
    __syncthreads();

    const int tstart = tile * TILE;

    // ---- prefetch registers (next iter's gather lives here) ----
    int g_idx;
    float g_p0, g_p1, g_p2;        // lanes<32: pos; lanes>=32: dir (same point)
    float4 g_a0, g_a1, g_a2, g_a3; // this lane's app half (16 floats)
    {
        int plc = tstart + w * PPW + p32;
        if (plc > cnt - 1) plc = cnt - 1;
        g_idx = perm[start + plc];
        const float4* ap = (const float4*)(app + g_idx * 32) + hf * 4;
        g_a0 = ap[0]; g_a1 = ap[1]; g_a2 = ap[2]; g_a3 = ap[3];
        const float* pd = (lane < 32) ? positions : directions;
        g_p0 = pd[g_idx * 3 + 0];
        g_p1 = pd[g_idx * 3 + 1];
        g_p2 = pd[g_idx * 3 + 2];
    }

#pragma unroll 1
    for (int it = 0; it < NIT; ++it) {
        const int pbase = tstart + it * 128 + w * PPW;
        if (pbase >= cnt) break;
        lfence();  // prior-iter LDS reads done before staging overwrite

        // ---- stage prefetched gather into LDS ----
        const int cur_idx = g_idx;
        if (lane < 32) {
            sIdx[w][p32] = g_idx;
            sPos[w][p32][0] = pk(g_p0, g_p1);
            sPos[w][p32][1] = pk(g_p2, 1.f);
        } else {
            u32x2 d2;
            d2.x = pk(g_p0, g_p1);
            d2.y = pk(g_p2, 1.f);
            *(u32x2*)&sCin[w][p32 * 72] = d2;
        }
        {
            u32x4 v0, v1;
            v0.x = pk(g_a0.x, g_a0.y); v0.y = pk(g_a0.z, g_a0.w);
            v0.z = pk(g_a1.x, g_a1.y); v0.w = pk(g_a1.z, g_a1.w);
            v1.x = pk(g_a2.x, g_a2.y); v1.y = pk(g_a2.z, g_a2.w);
            v1.z = pk(g_a3.x, g_a3.y); v1.w = pk(g_a3.z, g_a3.w);
            *(u32x4*)&sCin[w][p32 * 72 + 8 + hf * 16] = v0;
            *(u32x4*)&sCin[w][p32 * 72 + 16 + hf * 16] = v1;
        }
        lfence();

        // ---- issue next iter's gather (overlaps with compute below) ----
        {
            const int nbase = tstart + (it + 1) * 128 + w * PPW;
            if (it + 1 < NIT && nbase < cnt) {
                int plc = nbase + p32;
                if (plc > cnt - 1) plc = cnt - 1;
                g_idx = perm[start + plc];
                const float4* ap = (const float4*)(app + g_idx * 32) + hf * 4;
                g_a0 = ap[0]; g_a1 = ap[1]; g_a2 = ap[2]; g_a3 = ap[3];
                const float* pd = (lane < 32) ? positions : directions;
                g_p0 = pd[g_idx * 3 + 0];
                g_p1 = pd[g_idx * 3 + 1];
                g_p2 = pd[g_idx * 3 + 2];
            }
        }

        // ---- L1: h^T[128][32] = Wd1^T (A resident) x X^T (B from sPos) ----
        u32x2 xp0 = *(const u32x2*)&sPos[w][pt][0];
        u32x2 xp1 = *(const u32x2*)&sPos[w][16 + pt][0];
        u32x4 xv0; xv0.x = (quad == 0) ? xp0.x : 0u;
        xv0.y = (quad == 0) ? xp0.y : 0u; xv0.z = 0u; xv0.w = 0u;
        u32x4 xv1; xv1.x = (quad == 0) ? xp1.x : 0u;
        xv1.y = (quad == 0) ? xp1.y : 0u; xv1.z = 0u; xv1.w = 0u;
        const f16x8 xb0 = __builtin_bit_cast(f16x8, xv0);
        const f16x8 xb1 = __builtin_bit_cast(f16x8, xv1);
#pragma unroll
        for (int mt = 0; mt < 8; ++mt) {
            u32x4 av; av.x = wd1a0[mt]; av.y = wd1a1[mt]; av.z = 0u; av.w = 0u;
            f16x8 af = __builtin_bit_cast(f16x8, av);
            f32x4 acc0 = {0.f, 0.f, 0.f, 0.f};
            acc0 = __builtin_amdgcn_mfma_f32_16x16x32_f16(af, xb0, acc0, 0, 0, 0);
            f32x4 acc1 = {0.f, 0.f, 0.f, 0.f};
            acc1 = __builtin_amdgcn_mfma_f32_16x16x32_f16(af, xb1, acc1, 0, 0, 0);
            u32x2 hw0, hw1;
            hw0.x = pk(fmaxf(acc0[0], 0.f), fmaxf(acc0[1], 0.f));
            hw0.y = pk(fmaxf(acc0[2], 0.f), fmaxf(acc0[3], 0.f));
            hw1.x = pk(fmaxf(acc1[0], 0.f), fmaxf(acc1[1], 0.f));
            hw1.y = pk(fmaxf(acc1[2], 0.f), fmaxf(acc1[3], 0.f));
            // C: col=pt, row=quad*4+reg -> H[point][16mt+quad*4 ..+3]
            *(u32x2*)&sH[w][pt * 136 + 16 * mt + quad * 4] = hw0;
            *(u32x2*)&sH[w][(16 + pt) * 136 + 16 * mt + quad * 4] = hw1;
        }
        lfence();

        // ---- L2: dout[32x16] = h (A from sH) x Wd2 (B resident), bias C ----
        f32x4 dacc0 = {bd2v, bd2v, bd2v, bd2v};
        f32x4 dacc1 = {bd2v, bd2v, bd2v, bd2v};
#pragma unroll
        for (int s = 0; s < 4; ++s) {
            f16x8 ha0 = __builtin_bit_cast(f16x8,
                *(const u32x4*)&sH[w][pt * 136 + quad * 8 + 32 * s]);
            dacc0 = __builtin_amdgcn_mfma_f32_16x16x32_f16(ha0, wd2b[s], dacc0, 0, 0, 0);
            f16x8 ha1 = __builtin_bit_cast(f16x8,
                *(const u32x4*)&sH[w][(16 + pt) * 136 + quad * 8 + 32 * s]);
            dacc1 = __builtin_amdgcn_mfma_f32_16x16x32_f16(ha1, wd2b[s], dacc1, 0, 0, 0);
        }
        // C: col = o = pt, row = point = g*16 + quad*4 + reg
        if (pt == 0) {
            int4 si0 = *(const int4*)&sIdx[w][quad * 4];
            out[si0.x * 4] = __expf(dacc0[0]);
            out[si0.y * 4] = __expf(dacc0[1]);
            out[si0.z * 4] = __expf(dacc0[2]);
            out[si0.w * 4] = __expf(dacc0[3]);
            int4 si1 = *(const int4*)&sIdx[w][16 + quad * 4];
            out[si1.x * 4] = __expf(dacc1[0]);
            out[si1.y * 4] = __expf(dacc1[1]);
            out[si1.z * 4] = __expf(dacc1[2]);
            out[si1.w * 4] = __expf(dacc1[3]);
        } else {
#pragma unroll
            for (int r = 0; r < 4; ++r)
                sCin[w][(quad * 4 + r) * 72 + 40 + (pt - 1)] = (f16)dacc0[r];
#pragma unroll
            for (int r = 0; r < 4; ++r)
                sCin[w][(16 + quad * 4 + r) * 72 + 40 + (pt - 1)] = (f16)dacc1[r];
        }
        lfence();

        // ---- L3 (c1) + L4 (c2) fused per m-tile, both point groups ----
        const f16x8 cb00 = __builtin_bit_cast(f16x8,
            *(const u32x4*)&sCin[w][pt * 72 + quad * 8]);
        const f16x8 cb01 = __builtin_bit_cast(f16x8,
            *(const u32x4*)&sCin[w][pt * 72 + quad * 8 + 32]);
        const f16x8 cb10 = __builtin_bit_cast(f16x8,
            *(const u32x4*)&sCin[w][(16 + pt) * 72 + quad * 8]);
        const f16x8 cb11 = __builtin_bit_cast(f16x8,
            *(const u32x4*)&sCin[w][(16 + pt) * 72 + quad * 8 + 32]);
        float r00 = 0.f, r10 = 0.f, r20 = 0.f;
        float r01 = 0.f, r11 = 0.f, r21 = 0.f;
#pragma unroll
        for (int mt = 0; mt < 8; ++mt) {
            f16x8 wa0 = __builtin_bit_cast(f16x8,
                *(const u32x4*)&sWc1t[(16 * mt + pt) * 72 + quad * 8]);
            f16x8 wa1 = __builtin_bit_cast(f16x8,
                *(const u32x4*)&sWc1t[(16 * mt + pt) * 72 + quad * 8 + 32]);
            f32x4 cacc0 = {0.f, 0.f, 0.f, 0.f};
            cacc0 = __builtin_amdgcn_mfma_f32_16x16x32_f16(wa0, cb00, cacc0, 0, 0, 0);
            cacc0 = __builtin_amdgcn_mfma_f32_16x16x32_f16(wa1, cb01, cacc0, 0, 0, 0);
            f32x4 cacc1 = {0.f, 0.f, 0.f, 0.f};
            cacc1 = __builtin_amdgcn_mfma_f32_16x16x32_f16(wa0, cb10, cacc1, 0, 0, 0);
            cacc1 = __builtin_amdgcn_mfma_f32_16x16x32_f16(wa1, cb11, cacc1, 0, 0, 0);
            u32 h01_0 = pk(fmaxf(cacc0[0], 0.f), fmaxf(cacc0[1], 0.f));
            u32 h23_0 = pk(fmaxf(cacc0[2], 0.f), fmaxf(cacc0[3], 0.f));
            u32 h01_1 = pk(fmaxf(cacc1[0], 0.f), fmaxf(cacc1[1], 0.f));
            u32 h23_1 = pk(fmaxf(cacc1[2], 0.f), fmaxf(cacc1[3], 0.f));
            u32x4 w01 = *(const u32x4*)&sWc2p[(8 * mt + 2 * quad) * 4];
            u32x4 w23 = *(const u32x4*)&sWc2p[(8 * mt + 2 * quad + 1) * 4];
            r00 = dot2a(h01_0, w01.x, r00); r00 = dot2a(h23_0, w23.x, r00);
            r10 = dot2a(h01_0, w01.y, r10); r10 = dot2a(h23_0, w23.y, r10);
            r20 = dot2a(h01_0, w01.z, r20); r20 = dot2a(h23_0, w23.z, r20);
            r01 = dot2a(h01_1, w01.x, r01); r01 = dot2a(h23_1, w23.x, r01);
            r11 = dot2a(h01_1, w01.y, r11); r11 = dot2a(h23_1, w23.y, r11);
            r21 = dot2a(h01_1, w01.z, r21); r21 = dot2a(h23_1, w23.z, r21);
        }
        r00 += __shfl_xor(r00, 16, 64); r00 += __shfl_xor(r00, 32, 64);
        r10 += __shfl_xor(r10, 16, 64); r10 += __shfl_xor(r10, 32, 64);
        r20 += __shfl_xor(r20, 16, 64); r20 += __shfl_xor(r20, 32, 64);
        r01 += __shfl_xor(r01, 16, 64); r01 += __shfl_xor(r01, 32, 64);
        r11 += __shfl_xor(r11, 16, 64); r11 += __shfl_xor(r11, 32, 64);
        r21 += __shfl_xor(r21, 16, 64); r21 += __shfl_xor(r21, 32, 64);
        if (quad == 0) {       // lane owns point pt (g0): cur_idx matches
            float s0 = 1.f / (1.f + __expf(-(r00 + c20)));
            float s1 = 1.f / (1.f + __expf(-(r10 + c21)));
            float s2 = 1.f / (1.f + __expf(-(r20 + c22)));
            out[cur_idx * 4 + 1] = s0;
            *(float2*)&out[cur_idx * 4 + 2] = make_float2(s1, s2);
        } else if (quad == 1) {  // lane owns point 16+pt (g1): cur_idx matches
            float s0 = 1.f / (1.f + __expf(-(r01 + c20)));
            float s1 = 1.f / (1.f + __expf(-(r11 + c21)));
            float s2 = 1.f / (1.f + __expf(-(r21 + c22)));
            out[cur_idx * 4 + 1] = s0;
            *(float2*)&out[cur_idx * 4 + 2] = make_float2(s1, s2);
        }
    }
}

extern "C" void kernel_launch(void* const* d_in, const int* in_sizes, int n_in,
                              void* d_out, int out_size, void* d_ws, size_t ws_size,
                              hipStream_t stream) {
    const float* positions = (const float*)d_in[0];
    const float* directions = (const float*)d_in[1];
    const float* app = (const float*)d_in[2];
    const float* centroids = (const float*)d_in[3];
    const float* Wd1 = (const float*)d_in[4];
    const float* bd1 = (const float*)d_in[5];
    const float* Wd2 = (const float*)d_in[6];
    const float* bd2 = (const float*)d_in[7];
    const float* Wc1 = (const float*)d_in[8];
    const float* bc1 = (const float*)d_in[9];
    const float* Wc2 = (const float*)d_in[10];
    const float* bc2 = (const float*)d_in[11];
    float* out = (float*)d_out;
    int* wsi = (int*)d_ws;
    const int n = in_sizes[0] / 3;
    const int nb = (n + 2047) / 2048;   // 512 threads x 4 pts
    const int max_tiles = (n + TILE - 1) / TILE + NF;

    k_count<<<nb, 512, 0, stream>>>(positions, centroids, n, wsi + 32);
    k_scatscan<<<nb, 512, 0, stream>>>(positions, centroids, n, nb, wsi);
    k_main<<<max_tiles, 256, 0, stream>>>(positions, directions, app, Wd1, bd1, Wd2,
                                          bd2, Wc1, bc1, Wc2, bc2, wsi, nb, out);
}

// Round 6
// 74.878 us; speedup vs baseline: 1.0512x; 1.0512x over previous
//
#include <hip/hip_runtime.h>
#include <math.h>

#define NF 8
#define HID 128
#define NW 8       // waves per k_main block (share one weight-LDS copy)
#define TILE 1024  // points per k_main block: 8 waves x 16 pts x 8 iters
#define NIT 8

typedef _Float16 f16;
typedef _Float16 h2 __attribute__((ext_vector_type(2)));
typedef _Float16 f16x8 __attribute__((ext_vector_type(8)));
typedef float f32x4 __attribute__((ext_vector_type(4)));
typedef unsigned int u32;
typedef u32 u32x2 __attribute__((ext_vector_type(2)));
typedef u32 u32x4 __attribute__((ext_vector_type(4)));

__device__ __forceinline__ u32 pk(float a, float b) {
    return __builtin_bit_cast(u32, __builtin_amdgcn_cvt_pkrtz(a, b));
}
__device__ __forceinline__ float dot2a(u32 a, u32 b, float c) {
    return __builtin_amdgcn_fdot2(__builtin_bit_cast(h2, a),
                                  __builtin_bit_cast(h2, b), c, false);
}
__device__ __forceinline__ void lfence() {
    asm volatile("s_waitcnt lgkmcnt(0)" ::: "memory");
}

// ws int layout:
//   [0..7] counts, [8..15] starts, [16..23] tile-prefix, [24] total tiles
//   [32 .. 32+NB*8) per-block counts;  [32+NB*8 ..) perm

__device__ __forceinline__ int assign_field(float px, float py, float pz,
                                            const float* __restrict__ cen) {
    int best = 0;
    float bd = 3.4e38f;
#pragma unroll
    for (int k = 0; k < NF; ++k) {
        float dx = px - cen[k * 3 + 0];
        float dy = py - cen[k * 3 + 1];
        float dz = pz - cen[k * 3 + 2];
        float d = fmaf(dx, dx, fmaf(dy, dy, dz * dz));
        if (d < bd) { bd = d; best = k; }
    }
    return best;
}

// 512 threads, 4 points per thread; per-block counts only (no global atomics).
__global__ void k_count(const float* __restrict__ pos, const float* __restrict__ cen,
                        int n, int* __restrict__ blockcnt) {
    __shared__ int lc[NF];
    int tid = threadIdx.x;
    if (tid < NF) lc[tid] = 0;
    __syncthreads();
    int i4 = blockIdx.x * blockDim.x + tid;
    int base = i4 * 4;
    if (base + 3 < n) {
        const float4* p4 = (const float4*)pos;
        float4 a = p4[i4 * 3 + 0];
        float4 b = p4[i4 * 3 + 1];
        float4 c = p4[i4 * 3 + 2];
        atomicAdd(&lc[assign_field(a.x, a.y, a.z, cen)], 1);
        atomicAdd(&lc[assign_field(a.w, b.x, b.y, cen)], 1);
        atomicAdd(&lc[assign_field(b.z, b.w, c.x, cen)], 1);
        atomicAdd(&lc[assign_field(c.y, c.z, c.w, cen)], 1);
    } else {
        for (int i = base; i < n; ++i)
            atomicAdd(&lc[assign_field(pos[3 * i], pos[3 * i + 1], pos[3 * i + 2], cen)], 1);
    }
    __syncthreads();
    if (tid < NF) blockcnt[blockIdx.x * NF + tid] = lc[tid];
}

// Fused scan+scatter: every block redundantly scans the (nb x 8) count table
// (2 KB from L2), derives its own write offsets, then scatters its 4-pt chunk.
// Block 0 also writes the ws header. 512 threads; wave f owns field f in scan.
__global__ void k_scatscan(const float* __restrict__ pos, const float* __restrict__ cen,
                           int n, int nb, int* __restrict__ ws) {
    const int tid = threadIdx.x;
    const int f = tid >> 6, lane = tid & 63;
    const int* c = ws + 32;
    int* perm = ws + 32 + nb * NF;
    __shared__ int totals[NF], pres[NF], starts[NF], cur[NF];

    int tot = 0, pre = 0;
    for (int b = lane; b < nb; b += 64) {
        int v = c[b * NF + f];
        tot += v;
        if (b < (int)blockIdx.x) pre += v;
    }
#pragma unroll
    for (int d = 1; d < 64; d <<= 1) {
        tot += __shfl_xor(tot, d, 64);
        pre += __shfl_xor(pre, d, 64);
    }
    if (lane == 0) { totals[f] = tot; pres[f] = pre; }
    __syncthreads();
    if (tid == 0) {
        int s = 0, tp = 0;
        for (int k = 0; k < NF; ++k) {
            starts[k] = s;
            if (blockIdx.x == 0) {
                ws[k] = totals[k];
                ws[8 + k] = s;
                ws[16 + k] = tp;
            }
            s += totals[k];
            tp += (totals[k] + TILE - 1) / TILE;
        }
        if (blockIdx.x == 0) ws[24] = tp;
    }
    __syncthreads();
    if (tid < NF) cur[tid] = starts[tid] + pres[tid];
    __syncthreads();

    int i4 = blockIdx.x * blockDim.x + tid;
    int base = i4 * 4;
    if (base + 3 < n) {
        const float4* p4 = (const float4*)pos;
        float4 a = p4[i4 * 3 + 0];
        float4 b = p4[i4 * 3 + 1];
        float4 cc = p4[i4 * 3 + 2];
        int f0 = assign_field(a.x, a.y, a.z, cen);
        int f1 = assign_field(a.w, b.x, b.y, cen);
        int f2 = assign_field(b.z, b.w, cc.x, cen);
        int f3 = assign_field(cc.y, cc.z, cc.w, cen);
        perm[atomicAdd(&cur[f0], 1)] = base;
        perm[atomicAdd(&cur[f1], 1)] = base + 1;
        perm[atomicAdd(&cur[f2], 1)] = base + 2;
        perm[atomicAdd(&cur[f3], 1)] = base + 3;
    } else {
        for (int i = base; i < n; ++i) {
            int ff = assign_field(pos[3 * i], pos[3 * i + 1], pos[3 * i + 2], cen);
            perm[atomicAdd(&cur[ff], 1)] = i;
        }
    }
}

// MFMA k_main: 8-wave (512-thread) blocks sharing ONE weight-LDS copy
// (R0's 4-wave block duplicated 19KB of weights per block; merging two
// R0 blocks gives LDS 71.5KB -> 2 blocks/CU = 16 waves/CU, double R0's
// effective residency, with the per-wave pipeline unchanged).
// 3 fences/iter: the old post-STAGE fence was redundant (staged sCin/sIdx
// first read only after the L1->L2 lgkmcnt(0)).
// Per-wave structure = R0: 16 pts/iter, single-depth gather prefetch.
// cin layout per point (72 halves): [0..2]=dir, [3]=1(bias), [4..7]=0,
// [8..39]=app, [40..54]=geo, [55..63]=0. Wc1^T staged to match.
// Gather split: quad0=pos, quad3=dir, quad1/2=app halves.
__global__ __launch_bounds__(512, 2) void k_main(
    const float* __restrict__ positions, const float* __restrict__ directions,
    const float* __restrict__ app,
    const float* __restrict__ Wd1, const float* __restrict__ bd1,
    const float* __restrict__ Wd2, const float* __restrict__ bd2,
    const float* __restrict__ Wc1, const float* __restrict__ bc1,
    const float* __restrict__ Wc2, const float* __restrict__ bc2,
    const int* __restrict__ ws, int nb, float* __restrict__ out) {
    const int b = blockIdx.x;
    if (b >= ws[24]) return;
    int f = 0;
#pragma unroll
    for (int k = 1; k < NF; ++k) if (b >= ws[16 + k]) f = k;
    const int tile = b - ws[16 + f];
    const int cnt = ws[f];
    const int start = ws[8 + f];
    const int* perm = ws + 32 + nb * NF;
    const int tid = threadIdx.x;
    const int w = tid >> 6, lane = tid & 63;
    const int pt = lane & 15, quad = lane >> 4;

    __shared__ __align__(16) f16 sWc1t[HID * 72];    // [h][72] permuted  18 KB
    __shared__ __align__(16) u32 sWc2p[64 * 4];      // [hp][ch] pairs     1 KB
    __shared__ __align__(16) int sIdx[NW][16];       //                  0.5 KB
    __shared__ __align__(16) f16 sCin[NW][16 * 72];  // per-wave          18 KB
    __shared__ __align__(16) f16 sH[NW][16 * 136];   // per-wave          34 KB

    // ---- stage Wc1^T (permuted, f16) and Wc2 pairs ----
    if (tid < HID) {
        int h = tid;
        f16* row = &sWc1t[h * 72];
        const float* Wf = Wc1 + f * 50 * HID;
        row[0] = (f16)Wf[0 * HID + h];
        row[1] = (f16)Wf[1 * HID + h];
        row[2] = (f16)Wf[2 * HID + h];
        row[3] = (f16)bc1[f * HID + h];
        row[4] = 0; row[5] = 0; row[6] = 0; row[7] = 0;
        for (int a = 0; a < 32; ++a) row[8 + a] = (f16)Wf[(18 + a) * HID + h];
        for (int g = 0; g < 15; ++g) row[40 + g] = (f16)Wf[(3 + g) * HID + h];
        for (int z = 55; z < 72; ++z) row[z] = 0;
    }
    if (tid >= 128 && tid < 192) {
        int hp = tid - 128;
        const float* W2 = Wc2 + f * HID * 3;
        sWc2p[hp * 4 + 0] = pk(W2[(2 * hp) * 3 + 0], W2[(2 * hp + 1) * 3 + 0]);
        sWc2p[hp * 4 + 1] = pk(W2[(2 * hp) * 3 + 1], W2[(2 * hp + 1) * 3 + 1]);
        sWc2p[hp * 4 + 2] = pk(W2[(2 * hp) * 3 + 2], W2[(2 * hp + 1) * 3 + 2]);
        sWc2p[hp * 4 + 3] = 0;
    }
    if (lane < 16) {  // zero cin pad zones (per-wave region)
        f16* row = &sCin[w][pt * 72];
        u32x2 z2; z2.x = 0; z2.y = 0;
        *(u32x2*)&row[4] = z2;
        row[55] = 0;
        u32x4 z4; z4.x = 0; z4.y = 0; z4.z = 0; z4.w = 0;
        *(u32x4*)&row[56] = z4;
    }

    // ---- resident fragments (from global) ----
    u32 wd1a0[8], wd1a1[8];
    if (quad == 0) {
        const float* W1 = Wd1 + f * 3 * HID;
        const float* B1 = bd1 + f * HID;
#pragma unroll
        for (int mt = 0; mt < 8; ++mt) {
            int m = 16 * mt + pt;
            wd1a0[mt] = pk(W1[m], W1[HID + m]);
            wd1a1[mt] = pk(W1[2 * HID + m], B1[m]);
        }
    } else {
#pragma unroll
        for (int mt = 0; mt < 8; ++mt) { wd1a0[mt] = 0; wd1a1[mt] = 0; }
    }
    f16x8 wd2b[4];
    {
        const float* W2d = Wd2 + f * HID * 16;
#pragma unroll
        for (int s = 0; s < 4; ++s) {
            u32x4 v;
#pragma unroll
            for (int jp = 0; jp < 4; ++jp) {
                int k = quad * 8 + 32 * s + 2 * jp;
                v[jp] = pk(W2d[k * 16 + pt], W2d[(k + 1) * 16 + pt]);
            }
            wd2b[s] = __builtin_bit_cast(f16x8, v);
        }
    }
    const float bd2v = bd2[f * 16 + pt];
    const float c20 = bc2[f * 3 + 0], c21 = bc2[f * 3 + 1], c22 = bc2[f * 3 + 2];
    __syncthreads();

    const int tstart = tile * TILE;

    // ---- prefetch registers (iter's gather lives here one iter early) ----
    int g_idx;
    float4 g_p;                    // quad0: pos.xyz + 1
    float g_d0, g_d1, g_d2;        // quad3: dir
    float4 g_a0, g_a1, g_a2, g_a3; // quad1: app[0..15]; quad2: app[16..31]
    {
        int plc = tstart + w * 16 + pt;
        if (plc > cnt - 1) plc = cnt - 1;
        g_idx = perm[start + plc];
        if (quad == 0) {
            g_p = make_float4(positions[g_idx * 3 + 0], positions[g_idx * 3 + 1],
                              positions[g_idx * 3 + 2], 1.f);
        } else if (quad == 3) {
            g_d0 = directions[g_idx * 3 + 0];
            g_d1 = directions[g_idx * 3 + 1];
            g_d2 = directions[g_idx * 3 + 2];
        } else {
            const float4* ap = (const float4*)(app + g_idx * 32) + (quad == 2 ? 4 : 0);
            g_a0 = ap[0]; g_a1 = ap[1]; g_a2 = ap[2]; g_a3 = ap[3];
        }
    }

#pragma unroll 1
    for (int it = 0; it < NIT; ++it) {
        const int pbase = tstart + it * (NW * 16) + w * 16;
        if (pbase >= cnt) break;
        lfence();  // prior-iter LDS reads done before staging overwrite

        // ---- stage prefetched gather into LDS (drained by the L1 fence) ----
        const int cur_idx = g_idx;
        const float4 cur_p = g_p;
        if (quad == 0) {
            sIdx[w][pt] = g_idx;
        } else if (quad == 3) {
            u32x2 d2;
            d2.x = pk(g_d0, g_d1);
            d2.y = pk(g_d2, 1.f);
            *(u32x2*)&sCin[w][pt * 72] = d2;
        } else if (quad == 1) {
            u32x4 v0, v1;
            v0.x = pk(g_a0.x, g_a0.y); v0.y = pk(g_a0.z, g_a0.w);
            v0.z = pk(g_a1.x, g_a1.y); v0.w = pk(g_a1.z, g_a1.w);
            v1.x = pk(g_a2.x, g_a2.y); v1.y = pk(g_a2.z, g_a2.w);
            v1.z = pk(g_a3.x, g_a3.y); v1.w = pk(g_a3.z, g_a3.w);
            *(u32x4*)&sCin[w][pt * 72 + 8] = v0;
            *(u32x4*)&sCin[w][pt * 72 + 16] = v1;
        } else {
            u32x4 v0, v1;
            v0.x = pk(g_a0.x, g_a0.y); v0.y = pk(g_a0.z, g_a0.w);
            v0.z = pk(g_a1.x, g_a1.y); v0.w = pk(g_a1.z, g_a1.w);
            v1.x = pk(g_a2.x, g_a2.y); v1.y = pk(g_a2.z, g_a2.w);
            v1.z = pk(g_a3.x, g_a3.y); v1.w = pk(g_a3.z, g_a3.w);
            *(u32x4*)&sCin[w][pt * 72 + 24] = v0;
            *(u32x4*)&sCin[w][pt * 72 + 32] = v1;
        }

        // ---- issue next iter's gather (overlaps with compute below) ----
        {
            const int nbase = tstart + (it + 1) * (NW * 16) + w * 16;
            if (it + 1 < NIT && nbase < cnt) {
                int plc = nbase + pt;
                if (plc > cnt - 1) plc = cnt - 1;
                g_idx = perm[start + plc];
                if (quad == 0) {
                    g_p = make_float4(positions[g_idx * 3 + 0], positions[g_idx * 3 + 1],
                                      positions[g_idx * 3 + 2], 1.f);
                } else if (quad == 3) {
                    g_d0 = directions[g_idx * 3 + 0];
                    g_d1 = directions[g_idx * 3 + 1];
                    g_d2 = directions[g_idx * 3 + 2];
                } else {
                    const float4* ap = (const float4*)(app + g_idx * 32) + (quad == 2 ? 4 : 0);
                    g_a0 = ap[0]; g_a1 = ap[1]; g_a2 = ap[2]; g_a3 = ap[3];
                }
            }
        }

        // ---- L1 transposed: h^T[128x16] = Wd1^T (A resident) x X^T (B regs) ----
        u32 x01 = (quad == 0) ? pk(cur_p.x, cur_p.y) : 0u;
        u32 x23 = (quad == 0) ? pk(cur_p.z, cur_p.w) : 0u;
        u32x4 xv; xv.x = x01; xv.y = x23; xv.z = 0u; xv.w = 0u;
        const f16x8 xb = __builtin_bit_cast(f16x8, xv);
#pragma unroll
        for (int mt = 0; mt < 8; ++mt) {
            u32x4 av; av.x = wd1a0[mt]; av.y = wd1a1[mt]; av.z = 0u; av.w = 0u;
            f16x8 af = __builtin_bit_cast(f16x8, av);
            f32x4 acc = {0.f, 0.f, 0.f, 0.f};
            acc = __builtin_amdgcn_mfma_f32_16x16x32_f16(af, xb, acc, 0, 0, 0);
            u32x2 hw;
            hw.x = pk(fmaxf(acc[0], 0.f), fmaxf(acc[1], 0.f));
            hw.y = pk(fmaxf(acc[2], 0.f), fmaxf(acc[3], 0.f));
            // C: col=pt, row=quad*4+reg -> H[pt][16mt+quad*4 ..+3]
            *(u32x2*)&sH[w][pt * 136 + 16 * mt + quad * 4] = hw;
        }
        lfence();

        // ---- L2: dout[16x16] = h (A from H) x Wd2 (B resident), bias in C ----
        f32x4 dacc = {bd2v, bd2v, bd2v, bd2v};
#pragma unroll
        for (int s = 0; s < 4; ++s) {
            f16x8 ha = __builtin_bit_cast(f16x8,
                *(const u32x4*)&sH[w][pt * 136 + quad * 8 + 32 * s]);
            dacc = __builtin_amdgcn_mfma_f32_16x16x32_f16(ha, wd2b[s], dacc, 0, 0, 0);
        }
        // C: col = o = pt, row = point = quad*4+reg
        if (pt == 0) {
            int4 si = *(const int4*)&sIdx[w][quad * 4];
            out[si.x * 4] = __expf(dacc[0]);
            out[si.y * 4] = __expf(dacc[1]);
            out[si.z * 4] = __expf(dacc[2]);
            out[si.w * 4] = __expf(dacc[3]);
        } else {
#pragma unroll
            for (int r = 0; r < 4; ++r)
                sCin[w][(quad * 4 + r) * 72 + 40 + (pt - 1)] = (f16)dacc[r];
        }
        lfence();

        // ---- L3 transposed (c1) + L4 (c2) fused per m-tile ----
        const f16x8 cb0 = __builtin_bit_cast(f16x8,
            *(const u32x4*)&sCin[w][pt * 72 + quad * 8]);
        const f16x8 cb1 = __builtin_bit_cast(f16x8,
            *(const u32x4*)&sCin[w][pt * 72 + quad * 8 + 32]);
        float r0 = 0.f, r1 = 0.f, r2 = 0.f;
#pragma unroll
        for (int mt = 0; mt < 8; ++mt) {
            f16x8 wa0 = __builtin_bit_cast(f16x8,
                *(const u32x4*)&sWc1t[(16 * mt + pt) * 72 + quad * 8]);
            f16x8 wa1 = __builtin_bit_cast(f16x8,
                *(const u32x4*)&sWc1t[(16 * mt + pt) * 72 + quad * 8 + 32]);
            f32x4 cacc = {0.f, 0.f, 0.f, 0.f};
            cacc = __builtin_amdgcn_mfma_f32_16x16x32_f16(wa0, cb0, cacc, 0, 0, 0);
            cacc = __builtin_amdgcn_mfma_f32_16x16x32_f16(wa1, cb1, cacc, 0, 0, 0);
            // lane holds hc[hid=16mt+quad*4+reg][pt]
            u32 h01 = pk(fmaxf(cacc[0], 0.f), fmaxf(cacc[1], 0.f));
            u32 h23 = pk(fmaxf(cacc[2], 0.f), fmaxf(cacc[3], 0.f));
            u32x4 w01 = *(const u32x4*)&sWc2p[(8 * mt + 2 * quad) * 4];
            u32x4 w23 = *(const u32x4*)&sWc2p[(8 * mt + 2 * quad + 1) * 4];
            r0 = dot2a(h01, w01.x, r0); r0 = dot2a(h23, w23.x, r0);
            r1 = dot2a(h01, w01.y, r1); r1 = dot2a(h23, w23.y, r1);
            r2 = dot2a(h01, w01.z, r2); r2 = dot2a(h23, w23.z, r2);
        }
        r0 += __shfl_xor(r0, 16, 64); r0 += __shfl_xor(r0, 32, 64);
        r1 += __shfl_xor(r1, 16, 64); r1 += __shfl_xor(r1, 32, 64);
        r2 += __shfl_xor(r2, 16, 64); r2 += __shfl_xor(r2, 32, 64);
        if (quad == 0) {  // this lane staged pt -> cur_idx in register
            float s0 = 1.f / (1.f + __expf(-(r0 + c20)));
            float s1 = 1.f / (1.f + __expf(-(r1 + c21)));
            float s2 = 1.f / (1.f + __expf(-(r2 + c22)));
            out[cur_idx * 4 + 1] = s0;
            *(float2*)&out[cur_idx * 4 + 2] = make_float2(s1, s2);
        }
    }
}

extern "C" void kernel_launch(void* const* d_in, const int* in_sizes, int n_in,
                              void* d_out, int out_size, void* d_ws, size_t ws_size,
                              hipStream_t stream) {
    const float* positions = (const float*)d_in[0];
    const float* directions = (const float*)d_in[1];
    const float* app = (const float*)d_in[2];
    const float* centroids = (const float*)d_in[3];
    const float* Wd1 = (const float*)d_in[4];
    const float* bd1 = (const float*)d_in[5];
    const float* Wd2 = (const float*)d_in[6];
    const float* bd2 = (const float*)d_in[7];
    const float* Wc1 = (const float*)d_in[8];
    const float* bc1 = (const float*)d_in[9];
    const float* Wc2 = (const float*)d_in[10];
    const float* bc2 = (const float*)d_in[11];
    float* out = (float*)d_out;
    int* wsi = (int*)d_ws;
    const int n = in_sizes[0] / 3;
    const int nb = (n + 2047) / 2048;   // 512 threads x 4 pts
    const int max_tiles = (n + TILE - 1) / TILE + NF;

    k_count<<<nb, 512, 0, stream>>>(positions, centroids, n, wsi + 32);
    k_scatscan<<<nb, 512, 0, stream>>>(positions, centroids, n, nb, wsi);
    k_main<<<max_tiles, 512, 0, stream>>>(positions, directions, app, Wd1, bd1, Wd2,
                                          bd2, Wc1, bc1, Wc2, bc2, wsi, nb, out);
}